// Round 7
// baseline (255.780 us; speedup 1.0000x reference)
//
#include <hip/hip_runtime.h>
#include <hip/hip_bf16.h>

// TripletLoss: fused E·E^T + masked row min/max reduction. B=8192, D=256.
// dist = sqrt(2-2*sim) monotone decreasing in sim =>
//   dist_ap = dist(min sim over positives), dist_an = dist(max sim over negatives).
//
// R7: revert R6 (acc[4][4]+a[4][8] spilled: WRITE_SIZE 35MB). R4 inner structure
// (ms=4, nt=2, 128 VGPR) but grid 1024 blocks (256-col sweeps) + launch_bounds
// (256,4): 4 blocks/CU instead of grid-capped 2 -> double the latency-hiding TLP
// at identical per-iter cost. k=0 peeled with zero C-operand.

#define BDIM 8192
#define DDIM 256

typedef short bf16x8 __attribute__((ext_vector_type(8)));
typedef float f32x4  __attribute__((ext_vector_type(4)));
typedef unsigned short u16;

static __device__ __forceinline__ bf16x8 ld_frag(const u16* p) {
    return *reinterpret_cast<const bf16x8*>(p);
}

static __device__ __forceinline__ u16 f2bf(float f) {
    union { float f; unsigned int u; } x; x.f = f;
    unsigned int u = x.u;
    unsigned int r = u + 0x7fffu + ((u >> 16) & 1u);  // RNE
    return (u16)(r >> 16);
}

static __device__ __forceinline__ void gload_lds16(const u16* g, u16* l) {
    __builtin_amdgcn_global_load_lds(
        (const __attribute__((address_space(1))) unsigned int*)g,
        (__attribute__((address_space(3))) unsigned int*)l, 16, 0, 0);
}

// ---- kernel 1: fp32 -> bf16 convert + init reduction arrays ----
__global__ __launch_bounds__(256) void cvt_init_kernel(const float* __restrict__ in,
                                                       u16* __restrict__ out,
                                                       int* __restrict__ minpos,
                                                       int* __restrict__ maxneg) {
    int i = blockIdx.x * 256 + threadIdx.x;          // 524288 threads, 4 elems each
    const float4 v = reinterpret_cast<const float4*>(in)[i];
    ushort4 o;
    o.x = f2bf(v.x); o.y = f2bf(v.y); o.z = f2bf(v.z); o.w = f2bf(v.w);
    reinterpret_cast<ushort4*>(out)[i] = o;
    if (i < BDIM) {
        minpos[i] = 0x7f800000;                      // +inf  (min over positives of sim+2)
        maxneg[i] = 0;                               // 0.0f  (max over negatives of sim+2)
    }
}

// ---- kernel 2: fused GEMM + masked row min/max ----
// block = 256 thr = 4 waves; wave w owns rows [bx*256 + w*64, +64) (ms=4).
// Block sweeps 256 cols (by), 32 at a time (nt=2); B-tile 32x256 bf16 = 16KB,
// double-buffered, staged with global_load_lds w16; swizzle chunk c of row r
// at position c^(r&7) applied on the GLOBAL source address.
// Grid 32x32 = 1024 blocks -> 4 blocks/CU (VGPR<=128 via launch_bounds(256,4)).
__global__ __launch_bounds__(256, 4) void triplet_main(const u16* __restrict__ Ebf,
                                                       const int* __restrict__ labels,
                                                       int* __restrict__ minpos,
                                                       int* __restrict__ maxneg) {
    __shared__ __align__(16) u16 smem[2][32 * DDIM];  // 2 x 16 KB

    const int tid  = threadIdx.x;
    const int w    = tid >> 6;
    const int l    = tid & 63;
    const int quad = l >> 4;
    const int r16  = l & 15;

    const int mblk  = blockIdx.x * 256 + w * 64;     // wave's first row
    const int nbase = blockIdx.y * 256;

    // Preload A fragments: a[ms][k] covers rows [mblk+ms*16,+16), k-chunk [k*32,+32)
    bf16x8 a[4][8];
#pragma unroll
    for (int ms = 0; ms < 4; ++ms) {
        const u16* ap = Ebf + (size_t)(mblk + ms * 16 + r16) * DDIM + quad * 8;
#pragma unroll
        for (int k = 0; k < 8; ++k) a[ms][k] = ld_frag(ap + k * 32);
    }

    int lab_row[4][4];
#pragma unroll
    for (int ms = 0; ms < 4; ++ms)
#pragma unroll
        for (int r = 0; r < 4; ++r)
            lab_row[ms][r] = labels[mblk + ms * 16 + quad * 4 + r];

    float minp[4][4], maxn[4][4];
#pragma unroll
    for (int ms = 0; ms < 4; ++ms)
#pragma unroll
        for (int r = 0; r < 4; ++r) { minp[ms][r] = __builtin_inff(); maxn[ms][r] = -__builtin_inff(); }

    // swizzled-read lane constants
    const int qs = quad ^ (r16 & 3);                 // low-2-bit chunk index after swizzle
    const int s4 = (r16 >> 2) & 1;                   // bit-2 of swizzle

    // stage first tile (32 rows x 512B = 1024 chunks) into buf 0
#pragma unroll
    for (int it = 0; it < 4; ++it) {
        const int q = it * 256 + tid;
        const int r = q >> 5;
        const int c = (q & 31) ^ (r & 7);
        gload_lds16(Ebf + ((size_t)(nbase + r) << 8) + c * 8,
                    &smem[0][0] + it * 2048 + w * 512);
    }

    const f32x4 zero4 = (f32x4){0.f, 0.f, 0.f, 0.f};

    for (int nn = 0; nn < 8; ++nn) {
        const int cur = nn & 1;
        const int n0  = nbase + nn * 32;

        __syncthreads();   // staging of smem[cur] complete; smem[!cur] free

        if (nn + 1 < 8) {
            const int n1 = n0 + 32;
#pragma unroll
            for (int it = 0; it < 4; ++it) {
                const int q = it * 256 + tid;
                const int r = q >> 5;
                const int c = (q & 31) ^ (r & 7);
                gload_lds16(Ebf + ((size_t)(n1 + r) << 8) + c * 8,
                            &smem[cur ^ 1][0] + it * 2048 + w * 512);
            }
        }

        f32x4 acc[4][2];
        const u16* bb = &smem[cur][0];
        const u16* bnt[2];
#pragma unroll
        for (int nt = 0; nt < 2; ++nt)
            bnt[nt] = bb + (nt * 16 + r16) * DDIM + qs * 8;

        // k=0 peeled: C-operand is the zero vector (no acc re-zeroing)
        {
            const int koff = ((0 ^ s4) << 5);
            bf16x8 b[2];
#pragma unroll
            for (int nt = 0; nt < 2; ++nt) b[nt] = ld_frag(bnt[nt] + koff);
#pragma unroll
            for (int ms = 0; ms < 4; ++ms)
#pragma unroll
                for (int nt = 0; nt < 2; ++nt)
                    acc[ms][nt] = __builtin_amdgcn_mfma_f32_16x16x32_bf16(
                        a[ms][0], b[nt], zero4, 0, 0, 0);
        }
#pragma unroll
        for (int k = 1; k < 8; ++k) {
            const int koff = ((k ^ s4) << 5);
            bf16x8 b[2];
#pragma unroll
            for (int nt = 0; nt < 2; ++nt) b[nt] = ld_frag(bnt[nt] + koff);
#pragma unroll
            for (int ms = 0; ms < 4; ++ms)
#pragma unroll
                for (int nt = 0; nt < 2; ++nt)
                    acc[ms][nt] = __builtin_amdgcn_mfma_f32_16x16x32_bf16(
                        a[ms][k], b[nt], acc[ms][nt], 0, 0, 0);
        }

        // masked fold. Exact diag handling only where col range may hit row range.
        int lab_c[2];
#pragma unroll
        for (int nt = 0; nt < 2; ++nt) lab_c[nt] = labels[n0 + nt * 16 + r16];

        const bool diagTile = (n0 < mblk + 64) && (mblk < n0 + 32);
        if (__builtin_expect(diagTile, 0)) {
#pragma unroll
            for (int nt = 0; nt < 2; ++nt) {
                const int colg = n0 + nt * 16 + r16;
#pragma unroll
                for (int ms = 0; ms < 4; ++ms)
#pragma unroll
                    for (int r = 0; r < 4; ++r) {
                        const int rowg = mblk + ms * 16 + quad * 4 + r;
                        const float s = acc[ms][nt][r];
                        const bool same = (lab_c[nt] == lab_row[ms][r]);
                        const bool pos  = same && (colg != rowg);
                        minp[ms][r] = fminf(minp[ms][r], pos  ?  s : __builtin_inff());
                        maxn[ms][r] = fmaxf(maxn[ms][r], same ? -__builtin_inff() : s);
                    }
            }
        } else {
#pragma unroll
            for (int nt = 0; nt < 2; ++nt)
#pragma unroll
                for (int ms = 0; ms < 4; ++ms)
#pragma unroll
                    for (int r = 0; r < 4; ++r) {
                        const float s = acc[ms][nt][r];
                        const bool same = (lab_c[nt] == lab_row[ms][r]);
                        minp[ms][r] = fminf(minp[ms][r], same ?  s : __builtin_inff());
                        maxn[ms][r] = fmaxf(maxn[ms][r], same ? -__builtin_inff() : s);
                    }
        }
    }

    // reduce across the 16 lanes sharing a quad (same rows, different cols)
#pragma unroll
    for (int mask = 1; mask <= 8; mask <<= 1) {
#pragma unroll
        for (int ms = 0; ms < 4; ++ms)
#pragma unroll
            for (int r = 0; r < 4; ++r) {
                minp[ms][r] = fminf(minp[ms][r], __shfl_xor(minp[ms][r], mask, 64));
                maxn[ms][r] = fmaxf(maxn[ms][r], __shfl_xor(maxn[ms][r], mask, 64));
            }
    }
    if (r16 == 0) {
#pragma unroll
        for (int ms = 0; ms < 4; ++ms)
#pragma unroll
            for (int r = 0; r < 4; ++r) {
                const int rowg = mblk + ms * 16 + quad * 4 + r;
                atomicMin(minpos + rowg, __float_as_int(minp[ms][r] + 2.0f));
                atomicMax(maxneg + rowg, __float_as_int(maxn[ms][r] + 2.0f));
            }
    }
}

// ---- kernel 3: finalize (single block, 1024 threads) ----
__global__ __launch_bounds__(1024) void finalize_kernel(const int* __restrict__ minpos,
                                                        const int* __restrict__ maxneg,
                                                        float* __restrict__ out) {
    __shared__ float ssum[16], scnt[16];
    float sum = 0.f, cnt = 0.f;
#pragma unroll
    for (int it = 0; it < 8; ++it) {
        const int i = it * 1024 + threadIdx.x;
        const float mp = __int_as_float(minpos[i]);  // min(sim)+2 over positives; +inf if none
        const float mn = __int_as_float(maxneg[i]);  // max(sim)+2 over negatives; 0 if none
        if (mp < 1e30f && mn > 0.5f) {
            // dist = sqrt(2 - 2*sim), sim = stored - 2  =>  6 - 2*stored
            const float dap = sqrtf(fmaxf(6.0f - 2.0f * mp, 0.0f) + 1e-12f);
            const float dan = sqrtf(fmaxf(6.0f - 2.0f * mn, 0.0f) + 1e-12f);
            sum += fmaxf(dap - dan + 0.3f, 0.0f);
            cnt += 1.0f;
        }
    }
#pragma unroll
    for (int off = 32; off > 0; off >>= 1) {
        sum += __shfl_down(sum, off, 64);
        cnt += __shfl_down(cnt, off, 64);
    }
    const int wid = threadIdx.x >> 6;
    if ((threadIdx.x & 63) == 0) { ssum[wid] = sum; scnt[wid] = cnt; }
    __syncthreads();
    if (threadIdx.x == 0) {
        float S = 0.f, C = 0.f;
#pragma unroll
        for (int i = 0; i < 16; ++i) { S += ssum[i]; C += scnt[i]; }
        out[0] = (C > 0.f) ? (S / C) : 0.f;
    }
}

extern "C" void kernel_launch(void* const* d_in, const int* in_sizes, int n_in,
                              void* d_out, int out_size, void* d_ws, size_t ws_size,
                              hipStream_t stream) {
    const float* emb    = (const float*)d_in[0];
    const int*   labels = (const int*)d_in[1];
    float*       out    = (float*)d_out;

    u16* Ebf    = (u16*)d_ws;                                  // 4 MB
    int* minpos = (int*)((char*)d_ws + (size_t)BDIM * DDIM * 2);
    int* maxneg = minpos + BDIM;

    cvt_init_kernel<<<dim3((BDIM * DDIM / 4) / 256), dim3(256), 0, stream>>>(emb, Ebf, minpos, maxneg);
    triplet_main<<<dim3(BDIM / 256, BDIM / 256), dim3(256), 0, stream>>>(Ebf, labels, minpos, maxneg);
    finalize_kernel<<<dim3(1), dim3(1024), 0, stream>>>(minpos, maxneg, out);
}

// Round 8
// 115.736 us; speedup vs baseline: 2.2100x; 2.2100x over previous
//
#include <hip/hip_runtime.h>
#include <hip/hip_bf16.h>

// TripletLoss: fused E·E^T + masked row min/max reduction. B=8192, D=256.
// dist = sqrt(2-2*sim) monotone decreasing in sim =>
//   dist_ap = dist(min sim over positives), dist_an = dist(max sim over negatives).
//
// R8: R7's grid (1024 blocks, 256-col sweeps -> 4 blocks/CU possible) but
// launch_bounds back to (256,2): R7's (256,4) forced a 64-VGPR allocation and
// catastrophic spill (WRITE_SIZE 151MB). (256,2) reproduces R4's 128-VGPR
// no-spill allocation; HW residency 4 blocks/CU comes from resources
// (128 VGPR -> 4 waves/SIMD, 32KB LDS -> 5 blocks/CU), not the bound.

#define BDIM 8192
#define DDIM 256

typedef short bf16x8 __attribute__((ext_vector_type(8)));
typedef float f32x4  __attribute__((ext_vector_type(4)));
typedef unsigned short u16;

static __device__ __forceinline__ bf16x8 ld_frag(const u16* p) {
    return *reinterpret_cast<const bf16x8*>(p);
}

static __device__ __forceinline__ u16 f2bf(float f) {
    union { float f; unsigned int u; } x; x.f = f;
    unsigned int u = x.u;
    unsigned int r = u + 0x7fffu + ((u >> 16) & 1u);  // RNE
    return (u16)(r >> 16);
}

static __device__ __forceinline__ void gload_lds16(const u16* g, u16* l) {
    __builtin_amdgcn_global_load_lds(
        (const __attribute__((address_space(1))) unsigned int*)g,
        (__attribute__((address_space(3))) unsigned int*)l, 16, 0, 0);
}

// ---- kernel 1: fp32 -> bf16 convert + init reduction arrays ----
__global__ __launch_bounds__(256) void cvt_init_kernel(const float* __restrict__ in,
                                                       u16* __restrict__ out,
                                                       int* __restrict__ minpos,
                                                       int* __restrict__ maxneg) {
    int i = blockIdx.x * 256 + threadIdx.x;          // 524288 threads, 4 elems each
    const float4 v = reinterpret_cast<const float4*>(in)[i];
    ushort4 o;
    o.x = f2bf(v.x); o.y = f2bf(v.y); o.z = f2bf(v.z); o.w = f2bf(v.w);
    reinterpret_cast<ushort4*>(out)[i] = o;
    if (i < BDIM) {
        minpos[i] = 0x7f800000;                      // +inf  (min over positives of sim+2)
        maxneg[i] = 0;                               // 0.0f  (max over negatives of sim+2)
    }
}

// ---- kernel 2: fused GEMM + masked row min/max ----
// block = 256 thr = 4 waves; wave w owns rows [bx*256 + w*64, +64) (ms=4).
// Block sweeps 256 cols (by), 32 at a time (nt=2); B-tile 32x256 bf16 = 16KB,
// double-buffered, staged with global_load_lds w16; swizzle chunk c of row r
// at position c^(r&7) applied on the GLOBAL source address.
// Grid 32x32 = 1024 blocks; VGPR=128 (launch_bounds(256,2), same as R4).
__global__ __launch_bounds__(256, 2) void triplet_main(const u16* __restrict__ Ebf,
                                                       const int* __restrict__ labels,
                                                       int* __restrict__ minpos,
                                                       int* __restrict__ maxneg) {
    __shared__ __align__(16) u16 smem[2][32 * DDIM];  // 2 x 16 KB

    const int tid  = threadIdx.x;
    const int w    = tid >> 6;
    const int l    = tid & 63;
    const int quad = l >> 4;
    const int r16  = l & 15;

    const int mblk  = blockIdx.x * 256 + w * 64;     // wave's first row
    const int nbase = blockIdx.y * 256;

    // Preload A fragments: a[ms][k] covers rows [mblk+ms*16,+16), k-chunk [k*32,+32)
    bf16x8 a[4][8];
#pragma unroll
    for (int ms = 0; ms < 4; ++ms) {
        const u16* ap = Ebf + (size_t)(mblk + ms * 16 + r16) * DDIM + quad * 8;
#pragma unroll
        for (int k = 0; k < 8; ++k) a[ms][k] = ld_frag(ap + k * 32);
    }

    int lab_row[4][4];
#pragma unroll
    for (int ms = 0; ms < 4; ++ms)
#pragma unroll
        for (int r = 0; r < 4; ++r)
            lab_row[ms][r] = labels[mblk + ms * 16 + quad * 4 + r];

    float minp[4][4], maxn[4][4];
#pragma unroll
    for (int ms = 0; ms < 4; ++ms)
#pragma unroll
        for (int r = 0; r < 4; ++r) { minp[ms][r] = __builtin_inff(); maxn[ms][r] = -__builtin_inff(); }

    // swizzled-read lane constants
    const int qs = quad ^ (r16 & 3);                 // low-2-bit chunk index after swizzle
    const int s4 = (r16 >> 2) & 1;                   // bit-2 of swizzle

    // stage first tile (32 rows x 512B = 1024 chunks) into buf 0
#pragma unroll
    for (int it = 0; it < 4; ++it) {
        const int q = it * 256 + tid;
        const int r = q >> 5;
        const int c = (q & 31) ^ (r & 7);
        gload_lds16(Ebf + ((size_t)(nbase + r) << 8) + c * 8,
                    &smem[0][0] + it * 2048 + w * 512);
    }

    const f32x4 zero4 = (f32x4){0.f, 0.f, 0.f, 0.f};

    for (int nn = 0; nn < 8; ++nn) {
        const int cur = nn & 1;
        const int n0  = nbase + nn * 32;

        __syncthreads();   // staging of smem[cur] complete; smem[!cur] free

        if (nn + 1 < 8) {
            const int n1 = n0 + 32;
#pragma unroll
            for (int it = 0; it < 4; ++it) {
                const int q = it * 256 + tid;
                const int r = q >> 5;
                const int c = (q & 31) ^ (r & 7);
                gload_lds16(Ebf + ((size_t)(n1 + r) << 8) + c * 8,
                            &smem[cur ^ 1][0] + it * 2048 + w * 512);
            }
        }

        f32x4 acc[4][2];
        const u16* bb = &smem[cur][0];
        const u16* bnt[2];
#pragma unroll
        for (int nt = 0; nt < 2; ++nt)
            bnt[nt] = bb + (nt * 16 + r16) * DDIM + qs * 8;

        // k=0 peeled: C-operand is the zero vector (no acc re-zeroing)
        {
            const int koff = ((0 ^ s4) << 5);
            bf16x8 b[2];
#pragma unroll
            for (int nt = 0; nt < 2; ++nt) b[nt] = ld_frag(bnt[nt] + koff);
#pragma unroll
            for (int ms = 0; ms < 4; ++ms)
#pragma unroll
                for (int nt = 0; nt < 2; ++nt)
                    acc[ms][nt] = __builtin_amdgcn_mfma_f32_16x16x32_bf16(
                        a[ms][0], b[nt], zero4, 0, 0, 0);
        }
#pragma unroll
        for (int k = 1; k < 8; ++k) {
            const int koff = ((k ^ s4) << 5);
            bf16x8 b[2];
#pragma unroll
            for (int nt = 0; nt < 2; ++nt) b[nt] = ld_frag(bnt[nt] + koff);
#pragma unroll
            for (int ms = 0; ms < 4; ++ms)
#pragma unroll
                for (int nt = 0; nt < 2; ++nt)
                    acc[ms][nt] = __builtin_amdgcn_mfma_f32_16x16x32_bf16(
                        a[ms][k], b[nt], acc[ms][nt], 0, 0, 0);
        }

        // masked fold. Exact diag handling only where col range may hit row range.
        int lab_c[2];
#pragma unroll
        for (int nt = 0; nt < 2; ++nt) lab_c[nt] = labels[n0 + nt * 16 + r16];

        const bool diagTile = (n0 < mblk + 64) && (mblk < n0 + 32);
        if (__builtin_expect(diagTile, 0)) {
#pragma unroll
            for (int nt = 0; nt < 2; ++nt) {
                const int colg = n0 + nt * 16 + r16;
#pragma unroll
                for (int ms = 0; ms < 4; ++ms)
#pragma unroll
                    for (int r = 0; r < 4; ++r) {
                        const int rowg = mblk + ms * 16 + quad * 4 + r;
                        const float s = acc[ms][nt][r];
                        const bool same = (lab_c[nt] == lab_row[ms][r]);
                        const bool pos  = same && (colg != rowg);
                        minp[ms][r] = fminf(minp[ms][r], pos  ?  s : __builtin_inff());
                        maxn[ms][r] = fmaxf(maxn[ms][r], same ? -__builtin_inff() : s);
                    }
            }
        } else {
#pragma unroll
            for (int nt = 0; nt < 2; ++nt)
#pragma unroll
                for (int ms = 0; ms < 4; ++ms)
#pragma unroll
                    for (int r = 0; r < 4; ++r) {
                        const float s = acc[ms][nt][r];
                        const bool same = (lab_c[nt] == lab_row[ms][r]);
                        minp[ms][r] = fminf(minp[ms][r], same ?  s : __builtin_inff());
                        maxn[ms][r] = fmaxf(maxn[ms][r], same ? -__builtin_inff() : s);
                    }
        }
    }

    // reduce across the 16 lanes sharing a quad (same rows, different cols)
#pragma unroll
    for (int mask = 1; mask <= 8; mask <<= 1) {
#pragma unroll
        for (int ms = 0; ms < 4; ++ms)
#pragma unroll
            for (int r = 0; r < 4; ++r) {
                minp[ms][r] = fminf(minp[ms][r], __shfl_xor(minp[ms][r], mask, 64));
                maxn[ms][r] = fmaxf(maxn[ms][r], __shfl_xor(maxn[ms][r], mask, 64));
            }
    }
    if (r16 == 0) {
#pragma unroll
        for (int ms = 0; ms < 4; ++ms)
#pragma unroll
            for (int r = 0; r < 4; ++r) {
                const int rowg = mblk + ms * 16 + quad * 4 + r;
                atomicMin(minpos + rowg, __float_as_int(minp[ms][r] + 2.0f));
                atomicMax(maxneg + rowg, __float_as_int(maxn[ms][r] + 2.0f));
            }
    }
}

// ---- kernel 3: finalize (single block, 1024 threads) ----
__global__ __launch_bounds__(1024) void finalize_kernel(const int* __restrict__ minpos,
                                                        const int* __restrict__ maxneg,
                                                        float* __restrict__ out) {
    __shared__ float ssum[16], scnt[16];
    float sum = 0.f, cnt = 0.f;
#pragma unroll
    for (int it = 0; it < 8; ++it) {
        const int i = it * 1024 + threadIdx.x;
        const float mp = __int_as_float(minpos[i]);  // min(sim)+2 over positives; +inf if none
        const float mn = __int_as_float(maxneg[i]);  // max(sim)+2 over negatives; 0 if none
        if (mp < 1e30f && mn > 0.5f) {
            // dist = sqrt(2 - 2*sim), sim = stored - 2  =>  6 - 2*stored
            const float dap = sqrtf(fmaxf(6.0f - 2.0f * mp, 0.0f) + 1e-12f);
            const float dan = sqrtf(fmaxf(6.0f - 2.0f * mn, 0.0f) + 1e-12f);
            sum += fmaxf(dap - dan + 0.3f, 0.0f);
            cnt += 1.0f;
        }
    }
#pragma unroll
    for (int off = 32; off > 0; off >>= 1) {
        sum += __shfl_down(sum, off, 64);
        cnt += __shfl_down(cnt, off, 64);
    }
    const int wid = threadIdx.x >> 6;
    if ((threadIdx.x & 63) == 0) { ssum[wid] = sum; scnt[wid] = cnt; }
    __syncthreads();
    if (threadIdx.x == 0) {
        float S = 0.f, C = 0.f;
#pragma unroll
        for (int i = 0; i < 16; ++i) { S += ssum[i]; C += scnt[i]; }
        out[0] = (C > 0.f) ? (S / C) : 0.f;
    }
}

extern "C" void kernel_launch(void* const* d_in, const int* in_sizes, int n_in,
                              void* d_out, int out_size, void* d_ws, size_t ws_size,
                              hipStream_t stream) {
    const float* emb    = (const float*)d_in[0];
    const int*   labels = (const int*)d_in[1];
    float*       out    = (float*)d_out;

    u16* Ebf    = (u16*)d_ws;                                  // 4 MB
    int* minpos = (int*)((char*)d_ws + (size_t)BDIM * DDIM * 2);
    int* maxneg = minpos + BDIM;

    cvt_init_kernel<<<dim3((BDIM * DDIM / 4) / 256), dim3(256), 0, stream>>>(emb, Ebf, minpos, maxneg);
    triplet_main<<<dim3(BDIM / 256, BDIM / 256), dim3(256), 0, stream>>>(Ebf, labels, minpos, maxneg);
    finalize_kernel<<<dim3(1), dim3(1024), 0, stream>>>(minpos, maxneg, out);
}

// Round 9
// 105.878 us; speedup vs baseline: 2.4158x; 1.0931x over previous
//
#include <hip/hip_runtime.h>
#include <hip/hip_bf16.h>

// TripletLoss: fused E·E^T + masked row min/max reduction. B=8192, D=256.
// dist = sqrt(2-2*sim) monotone decreasing in sim =>
//   dist_ap = dist(min sim over positives), dist_an = dist(max sim over negatives).
//
// R9: R4 exact structure (grid 32x16, ms=4, nt=2, 128 VGPR, 2x16KB LDS dbuf) +
//  - full 5-bit XOR swizzle (chunk c of row r stored at c^r): ds_read_b128
//    becomes 2-way-per-phase (free) instead of 4 conflict cyc/read.
//  - staging-first prologue, labels loaded before the k-loop.
//  - cvt kernel 8 elems/thread (packed uint4 stores).

#define BDIM 8192
#define DDIM 256

typedef short bf16x8 __attribute__((ext_vector_type(8)));
typedef float f32x4  __attribute__((ext_vector_type(4)));
typedef unsigned short u16;
typedef unsigned int u32;

static __device__ __forceinline__ bf16x8 ld_frag(const u16* p) {
    return *reinterpret_cast<const bf16x8*>(p);
}

static __device__ __forceinline__ u32 f2bf(float f) {
    union { float f; u32 u; } x; x.f = f;
    u32 u = x.u;
    return (u + 0x7fffu + ((u >> 16) & 1u)) >> 16;   // RNE
}

static __device__ __forceinline__ void gload_lds16(const u16* g, u16* l) {
    __builtin_amdgcn_global_load_lds(
        (const __attribute__((address_space(1))) unsigned int*)g,
        (__attribute__((address_space(3))) unsigned int*)l, 16, 0, 0);
}

// ---- kernel 1: fp32 -> bf16 convert + init reduction arrays ----
__global__ __launch_bounds__(256) void cvt_init_kernel(const float* __restrict__ in,
                                                       u16* __restrict__ out,
                                                       int* __restrict__ minpos,
                                                       int* __restrict__ maxneg) {
    const int i = blockIdx.x * 256 + threadIdx.x;    // 262144 threads, 8 elems each
    const float4* in4 = reinterpret_cast<const float4*>(in);
    const float4 v0 = in4[2 * i];
    const float4 v1 = in4[2 * i + 1];
    uint4 o;
    o.x = f2bf(v0.x) | (f2bf(v0.y) << 16);
    o.y = f2bf(v0.z) | (f2bf(v0.w) << 16);
    o.z = f2bf(v1.x) | (f2bf(v1.y) << 16);
    o.w = f2bf(v1.z) | (f2bf(v1.w) << 16);
    reinterpret_cast<uint4*>(out)[i] = o;
    if (i < BDIM) {
        minpos[i] = 0x7f800000;                      // +inf  (min over positives of sim+2)
        maxneg[i] = 0;                               // 0.0f  (max over negatives of sim+2)
    }
}

// ---- kernel 2: fused GEMM + masked row min/max ----
// block = 256 thr = 4 waves; wave w owns rows [bx*256 + w*64, +64) (ms=4).
// Block sweeps 512 cols (by), 32 at a time (nt=2); B-tile 32x256 bf16 = 16KB,
// double-buffered, staged with global_load_lds w16. Swizzle: 16B chunk c of
// tile-local row r stored at position c^r (full 5-bit) -> conflict-free reads.
__global__ __launch_bounds__(256, 2) void triplet_main(const u16* __restrict__ Ebf,
                                                       const int* __restrict__ labels,
                                                       int* __restrict__ minpos,
                                                       int* __restrict__ maxneg) {
    __shared__ __align__(16) u16 smem[2][32 * DDIM];  // 2 x 16 KB

    const int tid  = threadIdx.x;
    const int w    = tid >> 6;
    const int l    = tid & 63;
    const int quad = l >> 4;
    const int r16  = l & 15;

    const int mblk  = blockIdx.x * 256 + w * 64;     // wave's first row
    const int nbase = blockIdx.y * 512;

    // stage first tile (32 rows x 512B = 1024 chunks) into buf 0 -- issue FIRST
#pragma unroll
    for (int it = 0; it < 4; ++it) {
        const int q = it * 256 + tid;
        const int r = q >> 5;                        // tile-local row 0..31
        const int c = (q & 31) ^ r;                  // 5-bit XOR swizzle
        gload_lds16(Ebf + ((size_t)(nbase + r) << 8) + c * 8,
                    &smem[0][0] + it * 2048 + w * 512);
    }

    // Preload A fragments: a[ms][k] covers rows [mblk+ms*16,+16), k-chunk [k*32,+32)
    bf16x8 a[4][8];
#pragma unroll
    for (int ms = 0; ms < 4; ++ms) {
        const u16* ap = Ebf + (size_t)(mblk + ms * 16 + r16) * DDIM + quad * 8;
#pragma unroll
        for (int k = 0; k < 8; ++k) a[ms][k] = ld_frag(ap + k * 32);
    }

    int lab_row[4][4];
#pragma unroll
    for (int ms = 0; ms < 4; ++ms)
#pragma unroll
        for (int r = 0; r < 4; ++r)
            lab_row[ms][r] = labels[mblk + ms * 16 + quad * 4 + r];

    float minp[4][4], maxn[4][4];
#pragma unroll
    for (int ms = 0; ms < 4; ++ms)
#pragma unroll
        for (int r = 0; r < 4; ++r) { minp[ms][r] = __builtin_inff(); maxn[ms][r] = -__builtin_inff(); }

    // swizzled-read lane constants: p = (4k+quad) ^ (nt*16+r16)
    //   low 2 bits:  qs  = quad ^ (r16 & 3)
    //   high 3 bits: k ^ (nt*4 + (r16 >> 2))
    const int qs  = quad ^ (r16 & 3);
    const int kx0 = (r16 >> 2);                      // nt=0
    const int kx1 = 4 + kx0;                         // nt=1

    const f32x4 zero4 = (f32x4){0.f, 0.f, 0.f, 0.f};

    for (int nn = 0; nn < 16; ++nn) {
        const int cur = nn & 1;
        const int n0  = nbase + nn * 32;

        __syncthreads();   // staging of smem[cur] complete; smem[!cur] free

        if (nn + 1 < 16) {
            const int n1 = n0 + 32;
#pragma unroll
            for (int it = 0; it < 4; ++it) {
                const int q = it * 256 + tid;
                const int r = q >> 5;
                const int c = (q & 31) ^ r;
                gload_lds16(Ebf + ((size_t)(n1 + r) << 8) + c * 8,
                            &smem[cur ^ 1][0] + it * 2048 + w * 512);
            }
        }

        // labels early -- latency hidden under the k-loop
        int lab_c[2];
#pragma unroll
        for (int nt = 0; nt < 2; ++nt) lab_c[nt] = labels[n0 + nt * 16 + r16];

        f32x4 acc[4][2];
        const u16* bb = &smem[cur][0];
        const u16* bnt[2];
#pragma unroll
        for (int nt = 0; nt < 2; ++nt)
            bnt[nt] = bb + (nt * 16 + r16) * DDIM + qs * 8;

        // k=0 peeled: C-operand is the zero vector (no acc re-zeroing)
        {
            bf16x8 b0 = ld_frag(bnt[0] + ((0 ^ kx0) << 5));
            bf16x8 b1 = ld_frag(bnt[1] + ((0 ^ kx1) << 5));
#pragma unroll
            for (int ms = 0; ms < 4; ++ms) {
                acc[ms][0] = __builtin_amdgcn_mfma_f32_16x16x32_bf16(a[ms][0], b0, zero4, 0, 0, 0);
                acc[ms][1] = __builtin_amdgcn_mfma_f32_16x16x32_bf16(a[ms][0], b1, zero4, 0, 0, 0);
            }
        }
#pragma unroll
        for (int k = 1; k < 8; ++k) {
            bf16x8 b0 = ld_frag(bnt[0] + ((k ^ kx0) << 5));
            bf16x8 b1 = ld_frag(bnt[1] + ((k ^ kx1) << 5));
#pragma unroll
            for (int ms = 0; ms < 4; ++ms) {
                acc[ms][0] = __builtin_amdgcn_mfma_f32_16x16x32_bf16(a[ms][k], b0, acc[ms][0], 0, 0, 0);
                acc[ms][1] = __builtin_amdgcn_mfma_f32_16x16x32_bf16(a[ms][k], b1, acc[ms][1], 0, 0, 0);
            }
        }

        // masked fold. Exact diag handling only where col range may hit row range.
        const bool diagTile = (n0 < mblk + 64) && (mblk < n0 + 32);
        if (__builtin_expect(diagTile, 0)) {
#pragma unroll
            for (int nt = 0; nt < 2; ++nt) {
                const int colg = n0 + nt * 16 + r16;
#pragma unroll
                for (int ms = 0; ms < 4; ++ms)
#pragma unroll
                    for (int r = 0; r < 4; ++r) {
                        const int rowg = mblk + ms * 16 + quad * 4 + r;
                        const float s = acc[ms][nt][r];
                        const bool same = (lab_c[nt] == lab_row[ms][r]);
                        const bool pos  = same && (colg != rowg);
                        minp[ms][r] = fminf(minp[ms][r], pos  ?  s : __builtin_inff());
                        maxn[ms][r] = fmaxf(maxn[ms][r], same ? -__builtin_inff() : s);
                    }
            }
        } else {
#pragma unroll
            for (int nt = 0; nt < 2; ++nt)
#pragma unroll
                for (int ms = 0; ms < 4; ++ms)
#pragma unroll
                    for (int r = 0; r < 4; ++r) {
                        const float s = acc[ms][nt][r];
                        const bool same = (lab_c[nt] == lab_row[ms][r]);
                        minp[ms][r] = fminf(minp[ms][r], same ?  s : __builtin_inff());
                        maxn[ms][r] = fmaxf(maxn[ms][r], same ? -__builtin_inff() : s);
                    }
        }
    }

    // reduce across the 16 lanes sharing a quad (same rows, different cols)
#pragma unroll
    for (int mask = 1; mask <= 8; mask <<= 1) {
#pragma unroll
        for (int ms = 0; ms < 4; ++ms)
#pragma unroll
            for (int r = 0; r < 4; ++r) {
                minp[ms][r] = fminf(minp[ms][r], __shfl_xor(minp[ms][r], mask, 64));
                maxn[ms][r] = fmaxf(maxn[ms][r], __shfl_xor(maxn[ms][r], mask, 64));
            }
    }
    if (r16 == 0) {
#pragma unroll
        for (int ms = 0; ms < 4; ++ms)
#pragma unroll
            for (int r = 0; r < 4; ++r) {
                const int rowg = mblk + ms * 16 + quad * 4 + r;
                atomicMin(minpos + rowg, __float_as_int(minp[ms][r] + 2.0f));
                atomicMax(maxneg + rowg, __float_as_int(maxn[ms][r] + 2.0f));
            }
    }
}

// ---- kernel 3: finalize (single block, 1024 threads) ----
__global__ __launch_bounds__(1024) void finalize_kernel(const int* __restrict__ minpos,
                                                        const int* __restrict__ maxneg,
                                                        float* __restrict__ out) {
    __shared__ float ssum[16], scnt[16];
    float sum = 0.f, cnt = 0.f;
#pragma unroll
    for (int it = 0; it < 8; ++it) {
        const int i = it * 1024 + threadIdx.x;
        const float mp = __int_as_float(minpos[i]);  // min(sim)+2 over positives; +inf if none
        const float mn = __int_as_float(maxneg[i]);  // max(sim)+2 over negatives; 0 if none
        if (mp < 1e30f && mn > 0.5f) {
            // dist = sqrt(2 - 2*sim), sim = stored - 2  =>  6 - 2*stored
            const float dap = sqrtf(fmaxf(6.0f - 2.0f * mp, 0.0f) + 1e-12f);
            const float dan = sqrtf(fmaxf(6.0f - 2.0f * mn, 0.0f) + 1e-12f);
            sum += fmaxf(dap - dan + 0.3f, 0.0f);
            cnt += 1.0f;
        }
    }
#pragma unroll
    for (int off = 32; off > 0; off >>= 1) {
        sum += __shfl_down(sum, off, 64);
        cnt += __shfl_down(cnt, off, 64);
    }
    const int wid = threadIdx.x >> 6;
    if ((threadIdx.x & 63) == 0) { ssum[wid] = sum; scnt[wid] = cnt; }
    __syncthreads();
    if (threadIdx.x == 0) {
        float S = 0.f, C = 0.f;
#pragma unroll
        for (int i = 0; i < 16; ++i) { S += ssum[i]; C += scnt[i]; }
        out[0] = (C > 0.f) ? (S / C) : 0.f;
    }
}

extern "C" void kernel_launch(void* const* d_in, const int* in_sizes, int n_in,
                              void* d_out, int out_size, void* d_ws, size_t ws_size,
                              hipStream_t stream) {
    const float* emb    = (const float*)d_in[0];
    const int*   labels = (const int*)d_in[1];
    float*       out    = (float*)d_out;

    u16* Ebf    = (u16*)d_ws;                                  // 4 MB
    int* minpos = (int*)((char*)d_ws + (size_t)BDIM * DDIM * 2);
    int* maxneg = minpos + BDIM;

    cvt_init_kernel<<<dim3((BDIM * DDIM / 8) / 256), dim3(256), 0, stream>>>(emb, Ebf, minpos, maxneg);
    triplet_main<<<dim3(BDIM / 256, BDIM / 512), dim3(256), 0, stream>>>(Ebf, labels, minpos, maxneg);
    finalize_kernel<<<dim3(1), dim3(1024), 0, stream>>>(minpos, maxneg, out);
}